// Round 1
// baseline (411.953 us; speedup 1.0000x reference)
//
#include <hip/hip_runtime.h>

#define RANK 256
#define NB 8192
#define NMAP 15625

typedef unsigned short ushort_t;
typedef short  mfma_ab __attribute__((ext_vector_type(8)));
typedef float  f32x4   __attribute__((ext_vector_type(4)));

// workspace byte offsets (total ~9.63 MB)
#define GEH_OFF   0          // 8192*256 bf16-high = 4,194,304
#define GEL_OFF   4194304    // 8192*256 bf16-low  = 4,194,304
#define WTH_OFF   8388608    // 4 mats * 256*256 bf16 = 524,288
#define WTL_OFF   8912896    // 524,288
#define INV_OFF   9437184    // 15625 int = 62,500
#define PARTS_OFF 9499712    // 128*256 f32 = 131,072
#define C2_OFF    9630784    // 256 f32

#define DD_BLOCKS 128        // edges per block = 2048 / 128 = 16

__device__ __forceinline__ float b2f(ushort_t u) {
    return __uint_as_float(((unsigned)u) << 16);
}
__device__ __forceinline__ ushort_t f2b(float f) {   // round-to-nearest-even
    unsigned u = __float_as_uint(f);
    return (ushort_t)((u + 0x7FFFu + ((u >> 16) & 1u)) >> 16);
}

__device__ __forceinline__ f32x4 mfma_bf16(mfma_ab a, mfma_ab b, f32x4 c) {
#if defined(__gfx950__)
    return __builtin_amdgcn_mfma_f32_16x16x32_bf16(a, b, c, 0, 0, 0);
#else
    (void)a; (void)b;
    return c;   // never executed on the target device (gfx950)
#endif
}

// ---------------------------------------------------------------- inv = -1
__global__ void k_init_inv(int* inv) {
    int i = blockIdx.x * 256 + threadIdx.x;
    if (i < NMAP) inv[i] = -1;
}

// ------------------------------------------------- inv[key_idx[b]] = b
__global__ void k_scatter(const int* key_ids, int* inv) {
    int b = blockIdx.x * 256 + threadIdx.x;
    const int* kp = key_ids + b * 6;
    int k = kp[0]*3125 + kp[1]*625 + kp[2]*125 + kp[3]*25 + kp[4]*5 + kp[5];
    inv[k] = b;
}

// ---------------- prep: split-transpose weights to [n][k] bf16 hi/lo -------
__global__ void k_prep_w(const float* __restrict__ sageW,
                         const float* __restrict__ predW1,
                         ushort_t* __restrict__ WTh,
                         ushort_t* __restrict__ WTl)
{
    const int id = blockIdx.x;
    const int mat = id >> 4, tile = id & 15;
    const int tr = tile >> 2, tc = tile & 3;
    const float* src = (mat < 3) ? (sageW + mat * 65536) : predW1;
    ushort_t* dh = WTh + mat * 65536;
    ushort_t* dl = WTl + mat * 65536;
    __shared__ float t[64][65];
    const int tid = threadIdx.x;
    const int c = tid & 63, r0 = tid >> 6;
    #pragma unroll
    for (int i = 0; i < 16; ++i) {
        int r = r0 + i * 4;
        t[r][c] = src[(tr*64 + r) * 256 + tc*64 + c];
    }
    __syncthreads();
    #pragma unroll
    for (int i = 0; i < 16; ++i) {
        int r = r0 + i * 4;
        float f = t[c][r];                       // = src[k = tr*64+c][n = tc*64+r]
        ushort_t h = f2b(f);
        dh[(tc*64 + r) * 256 + tr*64 + c] = h;   // WT[n][k]
        dl[(tc*64 + r) * 256 + tr*64 + c] = f2b(f - b2f(h));
    }
}

// ---------------- fused GraphReader: embed + 3x(SAGE->GEMM->LN->ReLU) ------
// block = 512 threads (8 waves), 5 graphs = 45 rows (pad 48)
// wave w owns output cols [w*32, w*32+32) = 2 N-tiles of 16
#define GR_G 5
#define GR_RPAD 48
#define AP 264   // bf16 split pitch (ushorts per row)

// Round-6 lesson: per-thread ARRAYS were lowered to scratch (SROA failure);
// everything is scalarized into named variables; no local arrays.
//
// This round: removed the fp32-master <-> bf16-split LDS *union* (cross-type
// aliasing of the same bytes was the last construct with compiler-memory-model
// risk; bench showed call-order-dependent divergence). Activations now live
// ONLY as hi/lo bf16 splits in sXh/sXl (ushort-typed end to end). hi+lo gives
// ~16-bit mantissa precision: rel err ~8e-6, negligible vs the 3.4e-3 thr.
// LDS footprint and barrier structure unchanged; MFMA phase unchanged.

#define LD_SPLIT4(V, IDX)                                                      \
    {                                                                          \
        const uint2 h_ = *(const uint2*)(sXh + (IDX));                         \
        const uint2 l_ = *(const uint2*)(sXl + (IDX));                         \
        V.x = __uint_as_float(h_.x << 16) + __uint_as_float(l_.x << 16);       \
        V.y = __uint_as_float(h_.x & 0xFFFF0000u) +                            \
              __uint_as_float(l_.x & 0xFFFF0000u);                             \
        V.z = __uint_as_float(h_.y << 16) + __uint_as_float(l_.y << 16);       \
        V.w = __uint_as_float(h_.y & 0xFFFF0000u) +                            \
              __uint_as_float(l_.y & 0xFFFF0000u);                             \
    }

#define ST_SPLIT4(IDX, V)                                                      \
    {                                                                          \
        const ushort_t h0_ = f2b(V.x), h1_ = f2b(V.y);                         \
        const ushort_t h2_ = f2b(V.z), h3_ = f2b(V.w);                         \
        const ushort_t l0_ = f2b(V.x - b2f(h0_)), l1_ = f2b(V.y - b2f(h1_));   \
        const ushort_t l2_ = f2b(V.z - b2f(h2_)), l3_ = f2b(V.w - b2f(h3_));   \
        *(uint2*)(sXh + (IDX)) =                                               \
            make_uint2((unsigned)h0_ | ((unsigned)h1_ << 16),                  \
                       (unsigned)h2_ | ((unsigned)h3_ << 16));                 \
        *(uint2*)(sXl + (IDX)) =                                               \
            make_uint2((unsigned)l0_ | ((unsigned)l1_ << 16),                  \
                       (unsigned)l2_ | ((unsigned)l3_ << 16));                 \
    }

#define AGG_LOAD(IT, V)                                                        \
    {                                                                          \
        const int t_ = tid + (IT) * 512;                                       \
        const int row_ = t_ >> 6, c4_ = t_ & 63;                               \
        V = make_float4(0.f, 0.f, 0.f, 0.f);                                   \
        if (row_ < nreal) {                                                    \
            const int j_ = row_ % 9;                                           \
            LD_SPLIT4(V, row_ * AP + c4_ * 4)                                  \
            float cnt_ = 1.f;                                                  \
            if (j_ > 0) {                                                      \
                float4 u_;                                                     \
                LD_SPLIT4(u_, (row_ - 1) * AP + c4_ * 4)                       \
                V.x += u_.x; V.y += u_.y; V.z += u_.z; V.w += u_.w; cnt_ += 1.f;\
            }                                                                  \
            if (j_ < 8) {                                                      \
                float4 u_;                                                     \
                LD_SPLIT4(u_, (row_ + 1) * AP + c4_ * 4)                       \
                V.x += u_.x; V.y += u_.y; V.z += u_.z; V.w += u_.w; cnt_ += 1.f;\
            }                                                                  \
            const float sc_ = 1.0f / cnt_;                                     \
            V.x *= sc_; V.y *= sc_; V.z *= sc_; V.w *= sc_;                    \
        }                                                                      \
    }

#define AGG_STORE(IT, V)                                                       \
    {                                                                          \
        const int t_ = tid + (IT) * 512;                                       \
        const int row_ = t_ >> 6, c4_ = t_ & 63;                               \
        ST_SPLIT4(row_ * AP + c4_ * 4, V)                                      \
    }

#define LN_PART(ACC0, ACC1, MT)                                                \
    _Pragma("unroll")                                                          \
    for (int q = 0; q < 4; ++q) {                                              \
        ACC0[q] += bias0; ACC1[q] += bias1;                                    \
        float s_  = ACC0[q] + ACC1[q];                                         \
        float ss_ = ACC0[q] * ACC0[q] + ACC1[q] * ACC1[q];                     \
        _Pragma("unroll")                                                      \
        for (int mask = 1; mask <= 8; mask <<= 1) {                            \
            s_  += __shfl_xor(s_, mask, 64);                                   \
            ss_ += __shfl_xor(ss_, mask, 64);                                  \
        }                                                                      \
        if (l15 == 0) sPart[(MT) * 16 + q4 * 4 + q][wid] = make_float2(s_, ss_);\
    }

#define LN_WRITE(ACC0, ACC1, MT)                                               \
    _Pragma("unroll")                                                          \
    for (int q = 0; q < 4; ++q) {                                              \
        const int row_ = (MT) * 16 + q4 * 4 + q;                               \
        const float2 mr_ = sMV[row_];                                          \
        float v0_ = (ACC0[q] - mr_.x) * mr_.y * gv0 + bv0;                     \
        float v1_ = (ACC1[q] - mr_.x) * mr_.y * gv1 + bv1;                     \
        v0_ = fmaxf(v0_, 0.f); v1_ = fmaxf(v1_, 0.f);                          \
        const ushort_t h0_ = f2b(v0_), h1_ = f2b(v1_);                         \
        const ushort_t l0_ = f2b(v0_ - b2f(h0_)), l1_ = f2b(v1_ - b2f(h1_));   \
        if (L < 2) {                                                           \
            sXh[row_ * AP + colb + l15]      = h0_;                            \
            sXl[row_ * AP + colb + l15]      = l0_;                            \
            sXh[row_ * AP + colb + 16 + l15] = h1_;                            \
            sXl[row_ * AP + colb + 16 + l15] = l1_;                            \
        } else if (row_ < nreal && (row_ % 9) == 0) {                          \
            const int gi_ = row_ / 9;                                          \
            GEh[(b0 + gi_) * RANK + colb + l15]      = h0_;                    \
            GEl[(b0 + gi_) * RANK + colb + l15]      = l0_;                    \
            GEh[(b0 + gi_) * RANK + colb + 16 + l15] = h1_;                    \
            GEl[(b0 + gi_) * RANK + colb + 16 + l15] = l1_;                    \
        }                                                                      \
    }

__global__ __launch_bounds__(512, 4) void k_graph_reader(
    const int* __restrict__ features,
    const float* __restrict__ emb,
    const ushort_t* __restrict__ WTh,
    const ushort_t* __restrict__ WTl,
    const float* __restrict__ sageB,
    const float* __restrict__ lnG,
    const float* __restrict__ lnB,
    ushort_t* __restrict__ GEh,
    ushort_t* __restrict__ GEl)
{
    // activations as hi/lo bf16 splits ONLY — single-type LDS, no unions.
    __shared__ __align__(16) ushort_t sXh[GR_RPAD * AP];   // 25,344 B
    __shared__ __align__(16) ushort_t sXl[GR_RPAD * AP];   // 25,344 B
    __shared__ float2 sPart[GR_RPAD][8];
    __shared__ float2 sMV[GR_RPAD];
    __shared__ int sFeat[GR_RPAD];

    const int tid  = threadIdx.x;
    const int wid  = tid >> 6;
    const int lane = tid & 63;
    const int q4   = lane >> 4;
    const int l15  = lane & 15;
    const int colb = wid * 32;

    const int b0    = blockIdx.x * GR_G;
    const int ngr   = min(GR_G, NB - b0);
    const int nreal = ngr * 9;

    if (tid < GR_RPAD) sFeat[tid] = (tid < nreal) ? features[b0 * 9 + tid] : 0;
    __syncthreads();

    // embed fill: 48 rows x 64 float4 chunks = 3072 tasks = 512*6
    // pad rows (>= nreal) are written as explicit zeros.
    #pragma unroll
    for (int it = 0; it < 6; ++it) {
        int t = tid + it * 512;
        int row = t >> 6, c4 = t & 63;
        float4 v = make_float4(0.f, 0.f, 0.f, 0.f);
        if (row < nreal)
            v = *(const float4*)(emb + sFeat[row] * RANK + c4 * 4);
        ST_SPLIT4(row * AP + c4 * 4, v)
    }

    const f32x4 vzero = {0.f, 0.f, 0.f, 0.f};

    for (int L = 0; L < 3; ++L) {
        float bias0, bias1, gv0, gv1, bv0, bv1;
        {
            int col0 = colb + l15, col1 = colb + 16 + l15;
            bias0 = sageB[L * RANK + col0]; bias1 = sageB[L * RANK + col1];
            gv0   = lnG[L * RANK + col0];   gv1   = lnG[L * RANK + col1];
            bv0   = lnB[L * RANK + col0];   bv1   = lnB[L * RANK + col1];
        }
        __syncthreads();   // sXh/sXl ready (embed or previous layer write-back)

        // phase 1: chain agg -> named registers (fp32, reconstructed hi+lo)
        float4 a0, a1, a2, a3, a4, a5;
        AGG_LOAD(0, a0) AGG_LOAD(1, a1) AGG_LOAD(2, a2)
        AGG_LOAD(3, a3) AGG_LOAD(4, a4) AGG_LOAD(5, a5)
        __syncthreads();   // all reads done -> safe to overwrite with agg splits

        // phase 2: split-write aggregate back into sXh/sXl (A-operand form)
        AGG_STORE(0, a0) AGG_STORE(1, a1) AGG_STORE(2, a2)
        AGG_STORE(3, a3) AGG_STORE(4, a4) AGG_STORE(5, a5)
        __syncthreads();   // A-operand ready

        // phase 3: split GEMM  [48 x 256] @ [256 x 256]
        f32x4 acc00 = vzero, acc01 = vzero;
        f32x4 acc10 = vzero, acc11 = vzero;
        f32x4 acc20 = vzero, acc21 = vzero;
        const ushort_t* bh = WTh + L * 65536 + (colb + l15) * RANK + q4 * 8;
        const ushort_t* bl = WTl + L * 65536 + (colb + l15) * RANK + q4 * 8;
        #pragma unroll
        for (int ks = 0; ks < 8; ++ks) {
            mfma_ab B0h = *(const mfma_ab*)(bh + ks * 32);
            mfma_ab B0l = *(const mfma_ab*)(bl + ks * 32);
            mfma_ab B1h = *(const mfma_ab*)(bh + 16 * RANK + ks * 32);
            mfma_ab B1l = *(const mfma_ab*)(bl + 16 * RANK + ks * 32);
            const int ab = l15 * AP + ks * 32 + q4 * 8;

            mfma_ab A0h = *(const mfma_ab*)(sXh + ab);
            mfma_ab A0l = *(const mfma_ab*)(sXl + ab);
            acc00 = mfma_bf16(A0h, B0h, acc00);
            acc00 = mfma_bf16(A0l, B0h, acc00);
            acc00 = mfma_bf16(A0h, B0l, acc00);
            acc01 = mfma_bf16(A0h, B1h, acc01);
            acc01 = mfma_bf16(A0l, B1h, acc01);
            acc01 = mfma_bf16(A0h, B1l, acc01);

            mfma_ab A1h = *(const mfma_ab*)(sXh + ab + 16 * AP);
            mfma_ab A1l = *(const mfma_ab*)(sXl + ab + 16 * AP);
            acc10 = mfma_bf16(A1h, B0h, acc10);
            acc10 = mfma_bf16(A1l, B0h, acc10);
            acc10 = mfma_bf16(A1h, B0l, acc10);
            acc11 = mfma_bf16(A1h, B1h, acc11);
            acc11 = mfma_bf16(A1l, B1h, acc11);
            acc11 = mfma_bf16(A1h, B1l, acc11);

            mfma_ab A2h = *(const mfma_ab*)(sXh + ab + 32 * AP);
            mfma_ab A2l = *(const mfma_ab*)(sXl + ab + 32 * AP);
            acc20 = mfma_bf16(A2h, B0h, acc20);
            acc20 = mfma_bf16(A2l, B0h, acc20);
            acc20 = mfma_bf16(A2h, B0l, acc20);
            acc21 = mfma_bf16(A2h, B1h, acc21);
            acc21 = mfma_bf16(A2l, B1h, acc21);
            acc21 = mfma_bf16(A2h, B1l, acc21);
        }

        // phase 4: bias + LN partials (C-layout: col = lane&15, row = q4*4+q)
        LN_PART(acc00, acc01, 0)
        LN_PART(acc10, acc11, 1)
        LN_PART(acc20, acc21, 2)
        __syncthreads();

        if (tid < GR_RPAD) {
            float s = 0.f, q = 0.f;
            #pragma unroll
            for (int w = 0; w < 8; ++w) { float2 p = sPart[tid][w]; s += p.x; q += p.y; }
            float m = s * (1.0f / 256.0f);
            float var = q * (1.0f / 256.0f) - m * m;
            if (var < 0.f) var = 0.f;
            sMV[tid] = make_float2(m, rsqrtf(var + 1e-5f));
        }
        __syncthreads();

        // phase 5: normalize + ReLU; write splits (or GE split on L==2)
        LN_WRITE(acc00, acc01, 0)
        LN_WRITE(acc10, acc11, 1)
        LN_WRITE(acc20, acc21, 2)
    }
}

// ---------------- dd aggregation partials (deterministic) ------------------
__global__ void k_dd_agg(const int* __restrict__ dd_src,
                         const int* __restrict__ inv,
                         const ushort_t* __restrict__ GEh,
                         const ushort_t* __restrict__ GEl,
                         float* __restrict__ parts)
{
    const int c  = threadIdx.x;
    const int e0 = blockIdx.x * (2048 / DD_BLOCKS);
    float s = 0.f;
    for (int e = e0; e < e0 + (2048 / DD_BLOCKS); ++e) {
        int b = inv[dd_src[e]];
        if (b >= 0) s += b2f(GEh[b * RANK + c]) + b2f(GEl[b * RANK + c]);
    }
    parts[blockIdx.x * RANK + c] = s;
}

// ---------------- device-node vector path -> c2 ----------------------------
__global__ void k_device(const float* __restrict__ parts,
                         const float* __restrict__ aug,
                         const float* __restrict__ infoW,
                         const float* __restrict__ infoB,
                         const float* __restrict__ ddW,
                         const float* __restrict__ ddB,
                         const float* __restrict__ normG,
                         const float* __restrict__ normB,
                         const float* __restrict__ predW1,
                         const float* __restrict__ predB1,
                         float* __restrict__ c2)
{
    __shared__ float sh[RANK];
    __shared__ float sdev[RANK];
    __shared__ float sred[RANK];
    const int n = threadIdx.x;

    float agg = 0.f;
    for (int p = 0; p < DD_BLOCKS; ++p) agg += parts[p * RANK + n];
    float info = infoB[n];
    for (int j = 0; j < 5; ++j) info += aug[j] * infoW[j * RANK + n];
    sh[n] = (agg + info) * (1.0f / 2049.0f);   // (agg + self) / (deg + 1)
    __syncthreads();

    float y = ddB[n];
    for (int k = 0; k < RANK; ++k) y += sh[k] * ddW[k * RANK + n];

    sred[n] = y; __syncthreads();
    for (int off = 128; off > 0; off >>= 1) {
        if (n < off) sred[n] += sred[n + off];
        __syncthreads();
    }
    float s = sred[0]; __syncthreads();
    sred[n] = y * y; __syncthreads();
    for (int off = 128; off > 0; off >>= 1) {
        if (n < off) sred[n] += sred[n + off];
        __syncthreads();
    }
    float q = sred[0]; __syncthreads();

    float m = s * (1.0f / 256.0f);
    float var = q * (1.0f / 256.0f) - m * m;
    if (var < 0.f) var = 0.f;
    float rs = rsqrtf(var + 1e-5f);
    float dev = (y - m) * rs * normG[n] + normB[n];
    if (dev < 0.f) dev = 0.f;
    sdev[n] = dev;
    __syncthreads();

    float o = predB1[n];
    for (int k = 0; k < RANK; ++k) o += sdev[k] * predW1[(RANK + k) * RANK + n];
    c2[n] = o;
}

// ---------------- final: out = relu(GE @ W1a + c2) . W2 + b2 ---------------
// block = 64 threads (1 wave) = 16 rows; split MFMA over full N=256
__global__ void k_pred(const ushort_t* __restrict__ GEh,
                       const ushort_t* __restrict__ GEl,
                       const ushort_t* __restrict__ W1h,   // [n][k] hi
                       const ushort_t* __restrict__ W1l,   // [n][k] lo
                       const float* __restrict__ c2,
                       const float* __restrict__ predW2,
                       const float* __restrict__ predB2,
                       float* __restrict__ out)
{
    const int lane = threadIdx.x;
    const int q4 = lane >> 4, l15 = lane & 15;
    const int m0 = blockIdx.x * 16;

    f32x4 acc[16];
    const f32x4 vzero = {0.f, 0.f, 0.f, 0.f};
    #pragma unroll
    for (int Nt = 0; Nt < 16; ++Nt) acc[Nt] = vzero;

    const ushort_t* ah = GEh + (m0 + l15) * RANK + q4 * 8;
    const ushort_t* al = GEl + (m0 + l15) * RANK + q4 * 8;
    const ushort_t* bh = W1h + l15 * RANK + q4 * 8;
    const ushort_t* bl = W1l + l15 * RANK + q4 * 8;
    #pragma unroll
    for (int ks = 0; ks < 8; ++ks) {
        mfma_ab Ah = *(const mfma_ab*)(ah + ks * 32);
        mfma_ab Al = *(const mfma_ab*)(al + ks * 32);
        #pragma unroll
        for (int Nt = 0; Nt < 16; ++Nt) {
            mfma_ab Bh = *(const mfma_ab*)(bh + Nt * 16 * RANK + ks * 32);
            mfma_ab Bl = *(const mfma_ab*)(bl + Nt * 16 * RANK + ks * 32);
            acc[Nt] = mfma_bf16(Ah, Bh, acc[Nt]);
            acc[Nt] = mfma_bf16(Al, Bh, acc[Nt]);
            acc[Nt] = mfma_bf16(Ah, Bl, acc[Nt]);
        }
    }

    float op0 = 0.f, op1 = 0.f, op2 = 0.f, op3 = 0.f;
    #pragma unroll
    for (int Nt = 0; Nt < 16; ++Nt) {
        int col = Nt * 16 + l15;
        float c2v = c2[col];
        float w2v = predW2[col];
        float h0 = fmaxf(acc[Nt][0] + c2v, 0.f);
        float h1 = fmaxf(acc[Nt][1] + c2v, 0.f);
        float h2 = fmaxf(acc[Nt][2] + c2v, 0.f);
        float h3 = fmaxf(acc[Nt][3] + c2v, 0.f);
        op0 += h0 * w2v; op1 += h1 * w2v; op2 += h2 * w2v; op3 += h3 * w2v;
    }
    #pragma unroll
    for (int mask = 1; mask <= 8; mask <<= 1) {
        op0 += __shfl_xor(op0, mask, 64);
        op1 += __shfl_xor(op1, mask, 64);
        op2 += __shfl_xor(op2, mask, 64);
        op3 += __shfl_xor(op3, mask, 64);
    }
    if (l15 == 0) {
        float b2 = predB2[0];
        out[m0 + q4 * 4 + 0] = op0 + b2;
        out[m0 + q4 * 4 + 1] = op1 + b2;
        out[m0 + q4 * 4 + 2] = op2 + b2;
        out[m0 + q4 * 4 + 3] = op3 + b2;
    }
}

extern "C" void kernel_launch(void* const* d_in, const int* in_sizes, int n_in,
                              void* d_out, int out_size, void* d_ws, size_t ws_size,
                              hipStream_t stream) {
    const int* features  = (const int*)d_in[0];
    const int* key_ids   = (const int*)d_in[1];
    const int* dd_src    = (const int*)d_in[4];
    const float* emb     = (const float*)d_in[5];
    const float* sageW   = (const float*)d_in[6];
    const float* sageB   = (const float*)d_in[7];
    const float* lnG     = (const float*)d_in[8];
    const float* lnB     = (const float*)d_in[9];
    const float* ddW     = (const float*)d_in[10];
    const float* ddB     = (const float*)d_in[11];
    const float* normG   = (const float*)d_in[12];
    const float* normB   = (const float*)d_in[13];
    const float* infoW   = (const float*)d_in[14];
    const float* infoB   = (const float*)d_in[15];
    const float* aug     = (const float*)d_in[16];
    const float* predW1  = (const float*)d_in[17];
    const float* predB1  = (const float*)d_in[18];
    const float* predW2  = (const float*)d_in[19];
    const float* predB2  = (const float*)d_in[20];

    char* ws = (char*)d_ws;
    ushort_t* GEh   = (ushort_t*)(ws + GEH_OFF);
    ushort_t* GEl   = (ushort_t*)(ws + GEL_OFF);
    ushort_t* WTh   = (ushort_t*)(ws + WTH_OFF);
    ushort_t* WTl   = (ushort_t*)(ws + WTL_OFF);
    int*      inv   = (int*)(ws + INV_OFF);
    float*    parts = (float*)(ws + PARTS_OFF);
    float*    c2    = (float*)(ws + C2_OFF);
    float*    outp  = (float*)d_out;

    k_init_inv<<<62, 256, 0, stream>>>(inv);
    k_scatter<<<32, 256, 0, stream>>>(key_ids, inv);
    k_prep_w<<<64, 256, 0, stream>>>(sageW, predW1, WTh, WTl);
    k_graph_reader<<<(NB + GR_G - 1) / GR_G, 512, 0, stream>>>(
        features, emb, WTh, WTl, sageB, lnG, lnB, GEh, GEl);
    k_dd_agg<<<DD_BLOCKS, 256, 0, stream>>>(dd_src, inv, GEh, GEl, parts);
    k_device<<<1, 256, 0, stream>>>(parts, aug, infoW, infoB, ddW, ddB,
                                    normG, normB, predW1, predB1, c2);
    k_pred<<<NB / 16, 64, 0, stream>>>(GEh, GEl, WTh + 3 * 65536, WTl + 3 * 65536,
                                       c2, predW2, predB2, outp);
}

// Round 7
// 401.018 us; speedup vs baseline: 1.0273x; 1.0273x over previous
//
#include <hip/hip_runtime.h>

#define RANK 256
#define NB 8192
#define NMAP 15625

typedef unsigned short ushort_t;
typedef short  mfma_ab __attribute__((ext_vector_type(8)));
typedef float  f32x4   __attribute__((ext_vector_type(4)));

// workspace byte offsets (total ~9.63 MB)
#define GEH_OFF   0          // 8192*256 bf16-high = 4,194,304
#define GEL_OFF   4194304    // 8192*256 bf16-low  = 4,194,304
#define WTH_OFF   8388608    // 4 mats * 256*256 bf16 = 524,288
#define WTL_OFF   8912896    // 524,288
#define INV_OFF   9437184    // 15625 int = 62,500
#define PARTS_OFF 9499712    // 128*256 f32 = 131,072
#define C2_OFF    9630784    // 256 f32

#define DD_BLOCKS 128        // edges per block = 2048 / 128 = 16

__device__ __forceinline__ float b2f(ushort_t u) {
    return __uint_as_float(((unsigned)u) << 16);
}
__device__ __forceinline__ ushort_t f2b(float f) {   // round-to-nearest-even
    unsigned u = __float_as_uint(f);
    return (ushort_t)((u + 0x7FFFu + ((u >> 16) & 1u)) >> 16);
}

__device__ __forceinline__ f32x4 mfma_bf16(mfma_ab a, mfma_ab b, f32x4 c) {
#if defined(__gfx950__)
    return __builtin_amdgcn_mfma_f32_16x16x32_bf16(a, b, c, 0, 0, 0);
#else
    (void)a; (void)b;
    return c;   // never executed on the target device (gfx950)
#endif
}

// ---------------------------------------------------------------- inv = -1
__global__ void k_init_inv(int* inv) {
    int i = blockIdx.x * 256 + threadIdx.x;
    if (i < NMAP) inv[i] = -1;
}

// ------------------------------------------------- inv[key_idx[b]] = b
__global__ void k_scatter(const int* key_ids, int* inv) {
    int b = blockIdx.x * 256 + threadIdx.x;
    const int* kp = key_ids + b * 6;
    int k = kp[0]*3125 + kp[1]*625 + kp[2]*125 + kp[3]*25 + kp[4]*5 + kp[5];
    inv[k] = b;
}

// ---------------- prep: split-transpose weights to [n][k] bf16 hi/lo -------
__global__ void k_prep_w(const float* __restrict__ sageW,
                         const float* __restrict__ predW1,
                         ushort_t* __restrict__ WTh,
                         ushort_t* __restrict__ WTl)
{
    const int id = blockIdx.x;
    const int mat = id >> 4, tile = id & 15;
    const int tr = tile >> 2, tc = tile & 3;
    const float* src = (mat < 3) ? (sageW + mat * 65536) : predW1;
    ushort_t* dh = WTh + mat * 65536;
    ushort_t* dl = WTl + mat * 65536;
    __shared__ float t[64][65];
    const int tid = threadIdx.x;
    const int c = tid & 63, r0 = tid >> 6;
    #pragma unroll
    for (int i = 0; i < 16; ++i) {
        int r = r0 + i * 4;
        t[r][c] = src[(tr*64 + r) * 256 + tc*64 + c];
    }
    __syncthreads();
    #pragma unroll
    for (int i = 0; i < 16; ++i) {
        int r = r0 + i * 4;
        float f = t[c][r];                       // = src[k = tr*64+c][n = tc*64+r]
        ushort_t h = f2b(f);
        dh[(tc*64 + r) * 256 + tr*64 + c] = h;   // WT[n][k]
        dl[(tc*64 + r) * 256 + tr*64 + c] = f2b(f - b2f(h));
    }
}

// ---------------- fused GraphReader: embed + 3x(SAGE->GEMM->LN->ReLU) ------
// block = 512 threads (8 waves), 5 graphs = 45 rows (pad 48)
// wave w owns output cols [w*32, w*32+32) = 2 N-tiles of 16
#define GR_G 5
#define GR_RPAD 48
#define AP 264   // bf16 split pitch (ushorts per row)

// Round-6 lesson: per-thread ARRAYS were lowered to scratch (SROA failure);
// everything is scalarized into named variables; no local arrays.
// Round-1 lesson (counters): VGPR_Count=64 + WRITE_SIZE=116MB => the allocator
// squeezed to the 8-wave/SIMD tier (useless: LDS caps us at 2 blocks/CU =
// 4 waves/SIMD) and spilled the agg registers that were live across a barrier.
// Fixes: (a) amdgpu_waves_per_eu(4,4) pins the 128-VGPR budget; (b) the chain
// aggregation is now WAVE-LOCAL (wave w owns graph w: lane = col-chunk,
// rolling 3-row window) so no register is live across any barrier and one
// barrier per layer is deleted. Summation order is kept bitwise identical
// ((left+cur)+right). Pad rows go stale instead of re-zeroed: harmless —
// agg never crosses graph boundaries, LN/GEMM are row-local, pads never emit.
// (Rounds 2-6 were infra failures — container/GPU never ran; resubmitting.)

#define LD_SPLIT4(V, IDX)                                                      \
    {                                                                          \
        const uint2 h_ = *(const uint2*)(sXh + (IDX));                         \
        const uint2 l_ = *(const uint2*)(sXl + (IDX));                         \
        V.x = __uint_as_float(h_.x << 16) + __uint_as_float(l_.x << 16);       \
        V.y = __uint_as_float(h_.x & 0xFFFF0000u) +                            \
              __uint_as_float(l_.x & 0xFFFF0000u);                             \
        V.z = __uint_as_float(h_.y << 16) + __uint_as_float(l_.y << 16);       \
        V.w = __uint_as_float(h_.y & 0xFFFF0000u) +                            \
              __uint_as_float(l_.y & 0xFFFF0000u);                             \
    }

#define ST_SPLIT4(IDX, V)                                                      \
    {                                                                          \
        const ushort_t h0_ = f2b(V.x), h1_ = f2b(V.y);                         \
        const ushort_t h2_ = f2b(V.z), h3_ = f2b(V.w);                         \
        const ushort_t l0_ = f2b(V.x - b2f(h0_)), l1_ = f2b(V.y - b2f(h1_));   \
        const ushort_t l2_ = f2b(V.z - b2f(h2_)), l3_ = f2b(V.w - b2f(h3_));   \
        *(uint2*)(sXh + (IDX)) =                                               \
            make_uint2((unsigned)h0_ | ((unsigned)h1_ << 16),                  \
                       (unsigned)h2_ | ((unsigned)h3_ << 16));                 \
        *(uint2*)(sXl + (IDX)) =                                               \
            make_uint2((unsigned)l0_ | ((unsigned)l1_ << 16),                  \
                       (unsigned)l2_ | ((unsigned)l3_ << 16));                 \
    }

#define LN_PART(ACC0, ACC1, MT)                                                \
    _Pragma("unroll")                                                          \
    for (int q = 0; q < 4; ++q) {                                              \
        ACC0[q] += bias0; ACC1[q] += bias1;                                    \
        float s_  = ACC0[q] + ACC1[q];                                         \
        float ss_ = ACC0[q] * ACC0[q] + ACC1[q] * ACC1[q];                     \
        _Pragma("unroll")                                                      \
        for (int mask = 1; mask <= 8; mask <<= 1) {                            \
            s_  += __shfl_xor(s_, mask, 64);                                   \
            ss_ += __shfl_xor(ss_, mask, 64);                                  \
        }                                                                      \
        if (l15 == 0) sPart[(MT) * 16 + q4 * 4 + q][wid] = make_float2(s_, ss_);\
    }

#define LN_WRITE(ACC0, ACC1, MT)                                               \
    _Pragma("unroll")                                                          \
    for (int q = 0; q < 4; ++q) {                                              \
        const int row_ = (MT) * 16 + q4 * 4 + q;                               \
        const float2 mr_ = sMV[row_];                                          \
        float v0_ = (ACC0[q] - mr_.x) * mr_.y * gv0 + bv0;                     \
        float v1_ = (ACC1[q] - mr_.x) * mr_.y * gv1 + bv1;                     \
        v0_ = fmaxf(v0_, 0.f); v1_ = fmaxf(v1_, 0.f);                          \
        const ushort_t h0_ = f2b(v0_), h1_ = f2b(v1_);                         \
        const ushort_t l0_ = f2b(v0_ - b2f(h0_)), l1_ = f2b(v1_ - b2f(h1_));   \
        if (L < 2) {                                                           \
            sXh[row_ * AP + colb + l15]      = h0_;                            \
            sXl[row_ * AP + colb + l15]      = l0_;                            \
            sXh[row_ * AP + colb + 16 + l15] = h1_;                            \
            sXl[row_ * AP + colb + 16 + l15] = l1_;                            \
        } else if (row_ < nreal && (row_ % 9) == 0) {                          \
            const int gi_ = row_ / 9;                                          \
            GEh[(b0 + gi_) * RANK + colb + l15]      = h0_;                    \
            GEl[(b0 + gi_) * RANK + colb + l15]      = l0_;                    \
            GEh[(b0 + gi_) * RANK + colb + 16 + l15] = h1_;                    \
            GEl[(b0 + gi_) * RANK + colb + 16 + l15] = l1_;                    \
        }                                                                      \
    }

__global__
__attribute__((amdgpu_flat_work_group_size(512, 512)))
__attribute__((amdgpu_waves_per_eu(4, 4)))
void k_graph_reader(
    const int* __restrict__ features,
    const float* __restrict__ emb,
    const ushort_t* __restrict__ WTh,
    const ushort_t* __restrict__ WTl,
    const float* __restrict__ sageB,
    const float* __restrict__ lnG,
    const float* __restrict__ lnB,
    ushort_t* __restrict__ GEh,
    ushort_t* __restrict__ GEl)
{
    // activations as hi/lo bf16 splits ONLY — single-type LDS, no unions.
    __shared__ __align__(16) ushort_t sXh[GR_RPAD * AP];   // 25,344 B
    __shared__ __align__(16) ushort_t sXl[GR_RPAD * AP];   // 25,344 B
    __shared__ float2 sPart[GR_RPAD][8];
    __shared__ float2 sMV[GR_RPAD];
    __shared__ int sFeat[GR_RPAD];

    const int tid  = threadIdx.x;
    const int wid  = tid >> 6;
    const int lane = tid & 63;
    const int q4   = lane >> 4;
    const int l15  = lane & 15;
    const int colb = wid * 32;

    const int b0    = blockIdx.x * GR_G;
    const int ngr   = min(GR_G, NB - b0);
    const int nreal = ngr * 9;

    if (tid < GR_RPAD) sFeat[tid] = (tid < nreal) ? features[b0 * 9 + tid] : 0;
    __syncthreads();

    // embed fill: 48 rows x 64 float4 chunks = 3072 tasks = 512*6
    // pad rows (>= nreal) are written as explicit zeros.
    #pragma unroll
    for (int it = 0; it < 6; ++it) {
        int t = tid + it * 512;
        int row = t >> 6, c4 = t & 63;
        float4 v = make_float4(0.f, 0.f, 0.f, 0.f);
        if (row < nreal)
            v = *(const float4*)(emb + sFeat[row] * RANK + c4 * 4);
        ST_SPLIT4(row * AP + c4 * 4, v)
    }

    const f32x4 vzero = {0.f, 0.f, 0.f, 0.f};

    for (int L = 0; L < 3; ++L) {
        float bias0, bias1, gv0, gv1, bv0, bv1;
        {
            int col0 = colb + l15, col1 = colb + 16 + l15;
            bias0 = sageB[L * RANK + col0]; bias1 = sageB[L * RANK + col1];
            gv0   = lnG[L * RANK + col0];   gv1   = lnG[L * RANK + col1];
            bv0   = lnB[L * RANK + col0];   bv1   = lnB[L * RANK + col1];
        }
        __syncthreads();   // sXh/sXl ready (embed or previous layer write-back)

        // phase 1+2 fused: WAVE-LOCAL chain agg, in-place. Wave w owns graph w
        // (rows 9w..9w+8); lane = 4-col chunk. One instruction stream => each
        // row is read (into the rolling window) strictly before it is
        // overwritten; no cross-wave row sharing; no barrier; no live-across-
        // barrier registers.
        if (wid < ngr) {
            const int gb = wid * 9 * AP + lane * 4;
            float4 pr_, cu_, nx_, ou_;
            LD_SPLIT4(pr_, gb)                       // row 0
            LD_SPLIT4(cu_, gb + AP)                  // row 1
            ou_.x = (pr_.x + cu_.x) * 0.5f;
            ou_.y = (pr_.y + cu_.y) * 0.5f;
            ou_.z = (pr_.z + cu_.z) * 0.5f;
            ou_.w = (pr_.w + cu_.w) * 0.5f;
            ST_SPLIT4(gb, ou_)                       // out row 0
            #pragma unroll
            for (int r = 1; r <= 7; ++r) {
                LD_SPLIT4(nx_, gb + (r + 1) * AP)    // row r+1
                const float th_ = 1.0f / 3.0f;
                ou_.x = (pr_.x + cu_.x + nx_.x) * th_;
                ou_.y = (pr_.y + cu_.y + nx_.y) * th_;
                ou_.z = (pr_.z + cu_.z + nx_.z) * th_;
                ou_.w = (pr_.w + cu_.w + nx_.w) * th_;
                ST_SPLIT4(gb + r * AP, ou_)          // out row r
                pr_ = cu_; cu_ = nx_;
            }
            ou_.x = (pr_.x + cu_.x) * 0.5f;
            ou_.y = (pr_.y + cu_.y) * 0.5f;
            ou_.z = (pr_.z + cu_.z) * 0.5f;
            ou_.w = (pr_.w + cu_.w) * 0.5f;
            ST_SPLIT4(gb + 8 * AP, ou_)              // out row 8
        }
        __syncthreads();   // A-operand ready

        // phase 3: split GEMM  [48 x 256] @ [256 x 256]
        f32x4 acc00 = vzero, acc01 = vzero;
        f32x4 acc10 = vzero, acc11 = vzero;
        f32x4 acc20 = vzero, acc21 = vzero;
        const ushort_t* bh = WTh + L * 65536 + (colb + l15) * RANK + q4 * 8;
        const ushort_t* bl = WTl + L * 65536 + (colb + l15) * RANK + q4 * 8;
        #pragma unroll
        for (int ks = 0; ks < 8; ++ks) {
            mfma_ab B0h = *(const mfma_ab*)(bh + ks * 32);
            mfma_ab B0l = *(const mfma_ab*)(bl + ks * 32);
            mfma_ab B1h = *(const mfma_ab*)(bh + 16 * RANK + ks * 32);
            mfma_ab B1l = *(const mfma_ab*)(bl + 16 * RANK + ks * 32);
            const int ab = l15 * AP + ks * 32 + q4 * 8;

            mfma_ab A0h = *(const mfma_ab*)(sXh + ab);
            mfma_ab A0l = *(const mfma_ab*)(sXl + ab);
            acc00 = mfma_bf16(A0h, B0h, acc00);
            acc00 = mfma_bf16(A0l, B0h, acc00);
            acc00 = mfma_bf16(A0h, B0l, acc00);
            acc01 = mfma_bf16(A0h, B1h, acc01);
            acc01 = mfma_bf16(A0l, B1h, acc01);
            acc01 = mfma_bf16(A0h, B1l, acc01);

            mfma_ab A1h = *(const mfma_ab*)(sXh + ab + 16 * AP);
            mfma_ab A1l = *(const mfma_ab*)(sXl + ab + 16 * AP);
            acc10 = mfma_bf16(A1h, B0h, acc10);
            acc10 = mfma_bf16(A1l, B0h, acc10);
            acc10 = mfma_bf16(A1h, B0l, acc10);
            acc11 = mfma_bf16(A1h, B1h, acc11);
            acc11 = mfma_bf16(A1l, B1h, acc11);
            acc11 = mfma_bf16(A1h, B1l, acc11);

            mfma_ab A2h = *(const mfma_ab*)(sXh + ab + 32 * AP);
            mfma_ab A2l = *(const mfma_ab*)(sXl + ab + 32 * AP);
            acc20 = mfma_bf16(A2h, B0h, acc20);
            acc20 = mfma_bf16(A2l, B0h, acc20);
            acc20 = mfma_bf16(A2h, B0l, acc20);
            acc21 = mfma_bf16(A2h, B1h, acc21);
            acc21 = mfma_bf16(A2l, B1h, acc21);
            acc21 = mfma_bf16(A2h, B1l, acc21);
        }

        // phase 4: bias + LN partials (C-layout: col = lane&15, row = q4*4+q)
        LN_PART(acc00, acc01, 0)
        LN_PART(acc10, acc11, 1)
        LN_PART(acc20, acc21, 2)
        __syncthreads();

        if (tid < GR_RPAD) {
            float s = 0.f, q = 0.f;
            #pragma unroll
            for (int w = 0; w < 8; ++w) { float2 p = sPart[tid][w]; s += p.x; q += p.y; }
            float m = s * (1.0f / 256.0f);
            float var = q * (1.0f / 256.0f) - m * m;
            if (var < 0.f) var = 0.f;
            sMV[tid] = make_float2(m, rsqrtf(var + 1e-5f));
        }
        __syncthreads();

        // phase 5: normalize + ReLU; write splits (or GE split on L==2)
        LN_WRITE(acc00, acc01, 0)
        LN_WRITE(acc10, acc11, 1)
        LN_WRITE(acc20, acc21, 2)
    }
}

// ---------------- dd aggregation partials (deterministic) ------------------
__global__ void k_dd_agg(const int* __restrict__ dd_src,
                         const int* __restrict__ inv,
                         const ushort_t* __restrict__ GEh,
                         const ushort_t* __restrict__ GEl,
                         float* __restrict__ parts)
{
    const int c  = threadIdx.x;
    const int e0 = blockIdx.x * (2048 / DD_BLOCKS);
    float s = 0.f;
    for (int e = e0; e < e0 + (2048 / DD_BLOCKS); ++e) {
        int b = inv[dd_src[e]];
        if (b >= 0) s += b2f(GEh[b * RANK + c]) + b2f(GEl[b * RANK + c]);
    }
    parts[blockIdx.x * RANK + c] = s;
}

// ---------------- device-node vector path -> c2 ----------------------------
__global__ void k_device(const float* __restrict__ parts,
                         const float* __restrict__ aug,
                         const float* __restrict__ infoW,
                         const float* __restrict__ infoB,
                         const float* __restrict__ ddW,
                         const float* __restrict__ ddB,
                         const float* __restrict__ normG,
                         const float* __restrict__ normB,
                         const float* __restrict__ predW1,
                         const float* __restrict__ predB1,
                         float* __restrict__ c2)
{
    __shared__ float sh[RANK];
    __shared__ float sdev[RANK];
    __shared__ float sred[RANK];
    const int n = threadIdx.x;

    float agg = 0.f;
    for (int p = 0; p < DD_BLOCKS; ++p) agg += parts[p * RANK + n];
    float info = infoB[n];
    for (int j = 0; j < 5; ++j) info += aug[j] * infoW[j * RANK + n];
    sh[n] = (agg + info) * (1.0f / 2049.0f);   // (agg + self) / (deg + 1)
    __syncthreads();

    float y = ddB[n];
    for (int k = 0; k < RANK; ++k) y += sh[k] * ddW[k * RANK + n];

    sred[n] = y; __syncthreads();
    for (int off = 128; off > 0; off >>= 1) {
        if (n < off) sred[n] += sred[n + off];
        __syncthreads();
    }
    float s = sred[0]; __syncthreads();
    sred[n] = y * y; __syncthreads();
    for (int off = 128; off > 0; off >>= 1) {
        if (n < off) sred[n] += sred[n + off];
        __syncthreads();
    }
    float q = sred[0]; __syncthreads();

    float m = s * (1.0f / 256.0f);
    float var = q * (1.0f / 256.0f) - m * m;
    if (var < 0.f) var = 0.f;
    float rs = rsqrtf(var + 1e-5f);
    float dev = (y - m) * rs * normG[n] + normB[n];
    if (dev < 0.f) dev = 0.f;
    sdev[n] = dev;
    __syncthreads();

    float o = predB1[n];
    for (int k = 0; k < RANK; ++k) o += sdev[k] * predW1[(RANK + k) * RANK + n];
    c2[n] = o;
}

// ---------------- final: out = relu(GE @ W1a + c2) . W2 + b2 ---------------
// block = 64 threads (1 wave) = 16 rows; split MFMA over full N=256
__global__ void k_pred(const ushort_t* __restrict__ GEh,
                       const ushort_t* __restrict__ GEl,
                       const ushort_t* __restrict__ W1h,   // [n][k] hi
                       const ushort_t* __restrict__ W1l,   // [n][k] lo
                       const float* __restrict__ c2,
                       const float* __restrict__ predW2,
                       const float* __restrict__ predB2,
                       float* __restrict__ out)
{
    const int lane = threadIdx.x;
    const int q4 = lane >> 4, l15 = lane & 15;
    const int m0 = blockIdx.x * 16;

    f32x4 acc[16];
    const f32x4 vzero = {0.f, 0.f, 0.f, 0.f};
    #pragma unroll
    for (int Nt = 0; Nt < 16; ++Nt) acc[Nt] = vzero;

    const ushort_t* ah = GEh + (m0 + l15) * RANK + q4 * 8;
    const ushort_t* al = GEl + (m0 + l15) * RANK + q4 * 8;
    const ushort_t* bh = W1h + l15 * RANK + q4 * 8;
    const ushort_t* bl = W1l + l15 * RANK + q4 * 8;
    #pragma unroll
    for (int ks = 0; ks < 8; ++ks) {
        mfma_ab Ah = *(const mfma_ab*)(ah + ks * 32);
        mfma_ab Al = *(const mfma_ab*)(al + ks * 32);
        #pragma unroll
        for (int Nt = 0; Nt < 16; ++Nt) {
            mfma_ab Bh = *(const mfma_ab*)(bh + Nt * 16 * RANK + ks * 32);
            mfma_ab Bl = *(const mfma_ab*)(bl + Nt * 16 * RANK + ks * 32);
            acc[Nt] = mfma_bf16(Ah, Bh, acc[Nt]);
            acc[Nt] = mfma_bf16(Al, Bh, acc[Nt]);
            acc[Nt] = mfma_bf16(Ah, Bl, acc[Nt]);
        }
    }

    float op0 = 0.f, op1 = 0.f, op2 = 0.f, op3 = 0.f;
    #pragma unroll
    for (int Nt = 0; Nt < 16; ++Nt) {
        int col = Nt * 16 + l15;
        float c2v = c2[col];
        float w2v = predW2[col];
        float h0 = fmaxf(acc[Nt][0] + c2v, 0.f);
        float h1 = fmaxf(acc[Nt][1] + c2v, 0.f);
        float h2 = fmaxf(acc[Nt][2] + c2v, 0.f);
        float h3 = fmaxf(acc[Nt][3] + c2v, 0.f);
        op0 += h0 * w2v; op1 += h1 * w2v; op2 += h2 * w2v; op3 += h3 * w2v;
    }
    #pragma unroll
    for (int mask = 1; mask <= 8; mask <<= 1) {
        op0 += __shfl_xor(op0, mask, 64);
        op1 += __shfl_xor(op1, mask, 64);
        op2 += __shfl_xor(op2, mask, 64);
        op3 += __shfl_xor(op3, mask, 64);
    }
    if (l15 == 0) {
        float b2 = predB2[0];
        out[m0 + q4 * 4 + 0] = op0 + b2;
        out[m0 + q4 * 4 + 1] = op1 + b2;
        out[m0 + q4 * 4 + 2] = op2 + b2;
        out[m0 + q4 * 4 + 3] = op3 + b2;
    }
}

extern "C" void kernel_launch(void* const* d_in, const int* in_sizes, int n_in,
                              void* d_out, int out_size, void* d_ws, size_t ws_size,
                              hipStream_t stream) {
    const int* features  = (const int*)d_in[0];
    const int* key_ids   = (const int*)d_in[1];
    const int* dd_src    = (const int*)d_in[4];
    const float* emb     = (const float*)d_in[5];
    const float* sageW   = (const float*)d_in[6];
    const float* sageB   = (const float*)d_in[7];
    const float* lnG     = (const float*)d_in[8];
    const float* lnB     = (const float*)d_in[9];
    const float* ddW     = (const float*)d_in[10];
    const float* ddB     = (const float*)d_in[11];
    const float* normG   = (const float*)d_in[12];
    const float* normB   = (const float*)d_in[13];
    const float* infoW   = (const float*)d_in[14];
    const float* infoB   = (const float*)d_in[15];
    const float* aug     = (const float*)d_in[16];
    const float* predW1  = (const float*)d_in[17];
    const float* predB1  = (const float*)d_in[18];
    const float* predW2  = (const float*)d_in[19];
    const float* predB2  = (const float*)d_in[20];

    char* ws = (char*)d_ws;
    ushort_t* GEh   = (ushort_t*)(ws + GEH_OFF);
    ushort_t* GEl   = (ushort_t*)(ws + GEL_OFF);
    ushort_t* WTh   = (ushort_t*)(ws + WTH_OFF);
    ushort_t* WTl   = (ushort_t*)(ws + WTL_OFF);
    int*      inv   = (int*)(ws + INV_OFF);
    float*    parts = (float*)(ws + PARTS_OFF);
    float*    c2    = (float*)(ws + C2_OFF);
    float*    outp  = (float*)d_out;

    k_init_inv<<<62, 256, 0, stream>>>(inv);
    k_scatter<<<32, 256, 0, stream>>>(key_ids, inv);
    k_prep_w<<<64, 256, 0, stream>>>(sageW, predW1, WTh, WTl);
    k_graph_reader<<<(NB + GR_G - 1) / GR_G, 512, 0, stream>>>(
        features, emb, WTh, WTl, sageB, lnG, lnB, GEh, GEl);
    k_dd_agg<<<DD_BLOCKS, 256, 0, stream>>>(dd_src, inv, GEh, GEl, parts);
    k_device<<<1, 256, 0, stream>>>(parts, aug, infoW, infoB, ddW, ddB,
                                    normG, normB, predW1, predB1, c2);
    k_pred<<<NB / 16, 64, 0, stream>>>(GEh, GEl, WTh + 3 * 65536, WTl + 3 * 65536,
                                       c2, predW2, predB2, outp);
}

// Round 8
// 398.547 us; speedup vs baseline: 1.0336x; 1.0062x over previous
//
#include <hip/hip_runtime.h>

#define RANK 256
#define NB 8192
#define NMAP 15625

typedef unsigned short ushort_t;
typedef short  mfma_ab __attribute__((ext_vector_type(8)));
typedef float  f32x4   __attribute__((ext_vector_type(4)));

// workspace byte offsets (total ~9.63 MB)
#define GEH_OFF   0          // 8192*256 bf16-high = 4,194,304
#define GEL_OFF   4194304    // 8192*256 bf16-low  = 4,194,304
#define WTH_OFF   8388608    // 4 mats * 256*256 bf16 = 524,288
#define WTL_OFF   8912896    // 524,288
#define INV_OFF   9437184    // 15625 int = 62,500
#define PARTS_OFF 9499712    // 128*256 f32 = 131,072
#define C2_OFF    9630784    // 256 f32

#define DD_BLOCKS 128        // edges per block = 2048 / 128 = 16

__device__ __forceinline__ float b2f(ushort_t u) {
    return __uint_as_float(((unsigned)u) << 16);
}
__device__ __forceinline__ ushort_t f2b(float f) {   // round-to-nearest-even
    unsigned u = __float_as_uint(f);
    return (ushort_t)((u + 0x7FFFu + ((u >> 16) & 1u)) >> 16);
}

__device__ __forceinline__ f32x4 mfma_bf16(mfma_ab a, mfma_ab b, f32x4 c) {
#if defined(__gfx950__)
    return __builtin_amdgcn_mfma_f32_16x16x32_bf16(a, b, c, 0, 0, 0);
#else
    (void)a; (void)b;
    return c;   // never executed on the target device (gfx950)
#endif
}

// ---------------------------------------------------------------- inv = -1
__global__ void k_init_inv(int* inv) {
    int i = blockIdx.x * 256 + threadIdx.x;
    if (i < NMAP) inv[i] = -1;
}

// ------------------------------------------------- inv[key_idx[b]] = b
__global__ void k_scatter(const int* key_ids, int* inv) {
    int b = blockIdx.x * 256 + threadIdx.x;
    const int* kp = key_ids + b * 6;
    int k = kp[0]*3125 + kp[1]*625 + kp[2]*125 + kp[3]*25 + kp[4]*5 + kp[5];
    inv[k] = b;
}

// ---------------- prep: split-transpose weights to [n][k] bf16 hi/lo -------
__global__ void k_prep_w(const float* __restrict__ sageW,
                         const float* __restrict__ predW1,
                         ushort_t* __restrict__ WTh,
                         ushort_t* __restrict__ WTl)
{
    const int id = blockIdx.x;
    const int mat = id >> 4, tile = id & 15;
    const int tr = tile >> 2, tc = tile & 3;
    const float* src = (mat < 3) ? (sageW + mat * 65536) : predW1;
    ushort_t* dh = WTh + mat * 65536;
    ushort_t* dl = WTl + mat * 65536;
    __shared__ float t[64][65];
    const int tid = threadIdx.x;
    const int c = tid & 63, r0 = tid >> 6;
    #pragma unroll
    for (int i = 0; i < 16; ++i) {
        int r = r0 + i * 4;
        t[r][c] = src[(tr*64 + r) * 256 + tc*64 + c];
    }
    __syncthreads();
    #pragma unroll
    for (int i = 0; i < 16; ++i) {
        int r = r0 + i * 4;
        float f = t[c][r];                       // = src[k = tr*64+c][n = tc*64+r]
        ushort_t h = f2b(f);
        dh[(tc*64 + r) * 256 + tr*64 + c] = h;   // WT[n][k]
        dl[(tc*64 + r) * 256 + tr*64 + c] = f2b(f - b2f(h));
    }
}

// ---------------- fused GraphReader: embed + 3x(SAGE->GEMM->LN->ReLU) ------
// block = 512 threads (8 waves), 5 graphs = 45 rows (pad 48)
// wave w owns output cols [w*32, w*32+32) = 2 N-tiles of 16
#define GR_G 5
#define GR_RPAD 48
#define AP 264   // bf16 split pitch (ushorts per row)

// Spill lineage (all at VGPR_Count=64): SROA-failure arrays 277 MB WRITE ->
// scalarized 116 MB -> wave-local agg 82 MB. Residual ~45 KB/block matches the
// acc[24]+LN-scalar live range crossing the two LN barriers. Both
// __launch_bounds__(512,4) and amdgpu_waves_per_eu(4,4) only CEILING the
// budget at 128; the occupancy heuristic still squeezed to the 64-tier and
// spilled (useless: LDS caps at 2 blocks/CU = 4 waves/SIMD = the 128 tier).
// Round-7 change: amdgpu_num_vgpr(128) requests the budget directly.

#define LD_SPLIT4(V, IDX)                                                      \
    {                                                                          \
        const uint2 h_ = *(const uint2*)(sXh + (IDX));                         \
        const uint2 l_ = *(const uint2*)(sXl + (IDX));                         \
        V.x = __uint_as_float(h_.x << 16) + __uint_as_float(l_.x << 16);       \
        V.y = __uint_as_float(h_.x & 0xFFFF0000u) +                            \
              __uint_as_float(l_.x & 0xFFFF0000u);                             \
        V.z = __uint_as_float(h_.y << 16) + __uint_as_float(l_.y << 16);       \
        V.w = __uint_as_float(h_.y & 0xFFFF0000u) +                            \
              __uint_as_float(l_.y & 0xFFFF0000u);                             \
    }

#define ST_SPLIT4(IDX, V)                                                      \
    {                                                                          \
        const ushort_t h0_ = f2b(V.x), h1_ = f2b(V.y);                         \
        const ushort_t h2_ = f2b(V.z), h3_ = f2b(V.w);                         \
        const ushort_t l0_ = f2b(V.x - b2f(h0_)), l1_ = f2b(V.y - b2f(h1_));   \
        const ushort_t l2_ = f2b(V.z - b2f(h2_)), l3_ = f2b(V.w - b2f(h3_));   \
        *(uint2*)(sXh + (IDX)) =                                               \
            make_uint2((unsigned)h0_ | ((unsigned)h1_ << 16),                  \
                       (unsigned)h2_ | ((unsigned)h3_ << 16));                 \
        *(uint2*)(sXl + (IDX)) =                                               \
            make_uint2((unsigned)l0_ | ((unsigned)l1_ << 16),                  \
                       (unsigned)l2_ | ((unsigned)l3_ << 16));                 \
    }

#define LN_PART(ACC0, ACC1, MT)                                                \
    _Pragma("unroll")                                                          \
    for (int q = 0; q < 4; ++q) {                                              \
        ACC0[q] += bias0; ACC1[q] += bias1;                                    \
        float s_  = ACC0[q] + ACC1[q];                                         \
        float ss_ = ACC0[q] * ACC0[q] + ACC1[q] * ACC1[q];                     \
        _Pragma("unroll")                                                      \
        for (int mask = 1; mask <= 8; mask <<= 1) {                            \
            s_  += __shfl_xor(s_, mask, 64);                                   \
            ss_ += __shfl_xor(ss_, mask, 64);                                  \
        }                                                                      \
        if (l15 == 0) sPart[(MT) * 16 + q4 * 4 + q][wid] = make_float2(s_, ss_);\
    }

#define LN_WRITE(ACC0, ACC1, MT)                                               \
    _Pragma("unroll")                                                          \
    for (int q = 0; q < 4; ++q) {                                              \
        const int row_ = (MT) * 16 + q4 * 4 + q;                               \
        const float2 mr_ = sMV[row_];                                          \
        float v0_ = (ACC0[q] - mr_.x) * mr_.y * gv0 + bv0;                     \
        float v1_ = (ACC1[q] - mr_.x) * mr_.y * gv1 + bv1;                     \
        v0_ = fmaxf(v0_, 0.f); v1_ = fmaxf(v1_, 0.f);                          \
        const ushort_t h0_ = f2b(v0_), h1_ = f2b(v1_);                         \
        const ushort_t l0_ = f2b(v0_ - b2f(h0_)), l1_ = f2b(v1_ - b2f(h1_));   \
        if (L < 2) {                                                           \
            sXh[row_ * AP + colb + l15]      = h0_;                            \
            sXl[row_ * AP + colb + l15]      = l0_;                            \
            sXh[row_ * AP + colb + 16 + l15] = h1_;                            \
            sXl[row_ * AP + colb + 16 + l15] = l1_;                            \
        } else if (row_ < nreal && (row_ % 9) == 0) {                          \
            const int gi_ = row_ / 9;                                          \
            GEh[(b0 + gi_) * RANK + colb + l15]      = h0_;                    \
            GEl[(b0 + gi_) * RANK + colb + l15]      = l0_;                    \
            GEh[(b0 + gi_) * RANK + colb + 16 + l15] = h1_;                    \
            GEl[(b0 + gi_) * RANK + colb + 16 + l15] = l1_;                    \
        }                                                                      \
    }

__global__
__attribute__((amdgpu_flat_work_group_size(512, 512)))
__attribute__((amdgpu_waves_per_eu(4, 4)))
__attribute__((amdgpu_num_vgpr(128)))
void k_graph_reader(
    const int* __restrict__ features,
    const float* __restrict__ emb,
    const ushort_t* __restrict__ WTh,
    const ushort_t* __restrict__ WTl,
    const float* __restrict__ sageB,
    const float* __restrict__ lnG,
    const float* __restrict__ lnB,
    ushort_t* __restrict__ GEh,
    ushort_t* __restrict__ GEl)
{
    // activations as hi/lo bf16 splits ONLY — single-type LDS, no unions.
    __shared__ __align__(16) ushort_t sXh[GR_RPAD * AP];   // 25,344 B
    __shared__ __align__(16) ushort_t sXl[GR_RPAD * AP];   // 25,344 B
    __shared__ float2 sPart[GR_RPAD][8];
    __shared__ float2 sMV[GR_RPAD];
    __shared__ int sFeat[GR_RPAD];

    const int tid  = threadIdx.x;
    const int wid  = tid >> 6;
    const int lane = tid & 63;
    const int q4   = lane >> 4;
    const int l15  = lane & 15;
    const int colb = wid * 32;

    const int b0    = blockIdx.x * GR_G;
    const int ngr   = min(GR_G, NB - b0);
    const int nreal = ngr * 9;

    if (tid < GR_RPAD) sFeat[tid] = (tid < nreal) ? features[b0 * 9 + tid] : 0;
    __syncthreads();

    // embed fill: 48 rows x 64 float4 chunks = 3072 tasks = 512*6
    // pad rows (>= nreal) are written as explicit zeros.
    #pragma unroll
    for (int it = 0; it < 6; ++it) {
        int t = tid + it * 512;
        int row = t >> 6, c4 = t & 63;
        float4 v = make_float4(0.f, 0.f, 0.f, 0.f);
        if (row < nreal)
            v = *(const float4*)(emb + sFeat[row] * RANK + c4 * 4);
        ST_SPLIT4(row * AP + c4 * 4, v)
    }

    const f32x4 vzero = {0.f, 0.f, 0.f, 0.f};

    for (int L = 0; L < 3; ++L) {
        float bias0, bias1, gv0, gv1, bv0, bv1;
        {
            int col0 = colb + l15, col1 = colb + 16 + l15;
            bias0 = sageB[L * RANK + col0]; bias1 = sageB[L * RANK + col1];
            gv0   = lnG[L * RANK + col0];   gv1   = lnG[L * RANK + col1];
            bv0   = lnB[L * RANK + col0];   bv1   = lnB[L * RANK + col1];
        }
        __syncthreads();   // sXh/sXl ready (embed or previous layer write-back)

        // phase 1+2 fused: WAVE-LOCAL chain agg, in-place. Wave w owns graph w
        // (rows 9w..9w+8); lane = 4-col chunk. One instruction stream => each
        // row is read (into the rolling window) strictly before it is
        // overwritten; no cross-wave row sharing; no barrier; no live-across-
        // barrier registers.
        if (wid < ngr) {
            const int gb = wid * 9 * AP + lane * 4;
            float4 pr_, cu_, nx_, ou_;
            LD_SPLIT4(pr_, gb)                       // row 0
            LD_SPLIT4(cu_, gb + AP)                  // row 1
            ou_.x = (pr_.x + cu_.x) * 0.5f;
            ou_.y = (pr_.y + cu_.y) * 0.5f;
            ou_.z = (pr_.z + cu_.z) * 0.5f;
            ou_.w = (pr_.w + cu_.w) * 0.5f;
            ST_SPLIT4(gb, ou_)                       // out row 0
            #pragma unroll
            for (int r = 1; r <= 7; ++r) {
                LD_SPLIT4(nx_, gb + (r + 1) * AP)    // row r+1
                const float th_ = 1.0f / 3.0f;
                ou_.x = (pr_.x + cu_.x + nx_.x) * th_;
                ou_.y = (pr_.y + cu_.y + nx_.y) * th_;
                ou_.z = (pr_.z + cu_.z + nx_.z) * th_;
                ou_.w = (pr_.w + cu_.w + nx_.w) * th_;
                ST_SPLIT4(gb + r * AP, ou_)          // out row r
                pr_ = cu_; cu_ = nx_;
            }
            ou_.x = (pr_.x + cu_.x) * 0.5f;
            ou_.y = (pr_.y + cu_.y) * 0.5f;
            ou_.z = (pr_.z + cu_.z) * 0.5f;
            ou_.w = (pr_.w + cu_.w) * 0.5f;
            ST_SPLIT4(gb + 8 * AP, ou_)              // out row 8
        }
        __syncthreads();   // A-operand ready

        // phase 3: split GEMM  [48 x 256] @ [256 x 256]
        f32x4 acc00 = vzero, acc01 = vzero;
        f32x4 acc10 = vzero, acc11 = vzero;
        f32x4 acc20 = vzero, acc21 = vzero;
        const ushort_t* bh = WTh + L * 65536 + (colb + l15) * RANK + q4 * 8;
        const ushort_t* bl = WTl + L * 65536 + (colb + l15) * RANK + q4 * 8;
        #pragma unroll
        for (int ks = 0; ks < 8; ++ks) {
            mfma_ab B0h = *(const mfma_ab*)(bh + ks * 32);
            mfma_ab B0l = *(const mfma_ab*)(bl + ks * 32);
            mfma_ab B1h = *(const mfma_ab*)(bh + 16 * RANK + ks * 32);
            mfma_ab B1l = *(const mfma_ab*)(bl + 16 * RANK + ks * 32);
            const int ab = l15 * AP + ks * 32 + q4 * 8;

            mfma_ab A0h = *(const mfma_ab*)(sXh + ab);
            mfma_ab A0l = *(const mfma_ab*)(sXl + ab);
            acc00 = mfma_bf16(A0h, B0h, acc00);
            acc00 = mfma_bf16(A0l, B0h, acc00);
            acc00 = mfma_bf16(A0h, B0l, acc00);
            acc01 = mfma_bf16(A0h, B1h, acc01);
            acc01 = mfma_bf16(A0l, B1h, acc01);
            acc01 = mfma_bf16(A0h, B1l, acc01);

            mfma_ab A1h = *(const mfma_ab*)(sXh + ab + 16 * AP);
            mfma_ab A1l = *(const mfma_ab*)(sXl + ab + 16 * AP);
            acc10 = mfma_bf16(A1h, B0h, acc10);
            acc10 = mfma_bf16(A1l, B0h, acc10);
            acc10 = mfma_bf16(A1h, B0l, acc10);
            acc11 = mfma_bf16(A1h, B1h, acc11);
            acc11 = mfma_bf16(A1l, B1h, acc11);
            acc11 = mfma_bf16(A1h, B1l, acc11);

            mfma_ab A2h = *(const mfma_ab*)(sXh + ab + 32 * AP);
            mfma_ab A2l = *(const mfma_ab*)(sXl + ab + 32 * AP);
            acc20 = mfma_bf16(A2h, B0h, acc20);
            acc20 = mfma_bf16(A2l, B0h, acc20);
            acc20 = mfma_bf16(A2h, B0l, acc20);
            acc21 = mfma_bf16(A2h, B1h, acc21);
            acc21 = mfma_bf16(A2l, B1h, acc21);
            acc21 = mfma_bf16(A2h, B1l, acc21);
        }

        // phase 4: bias + LN partials (C-layout: col = lane&15, row = q4*4+q)
        LN_PART(acc00, acc01, 0)
        LN_PART(acc10, acc11, 1)
        LN_PART(acc20, acc21, 2)
        __syncthreads();

        if (tid < GR_RPAD) {
            float s = 0.f, q = 0.f;
            #pragma unroll
            for (int w = 0; w < 8; ++w) { float2 p = sPart[tid][w]; s += p.x; q += p.y; }
            float m = s * (1.0f / 256.0f);
            float var = q * (1.0f / 256.0f) - m * m;
            if (var < 0.f) var = 0.f;
            sMV[tid] = make_float2(m, rsqrtf(var + 1e-5f));
        }
        __syncthreads();

        // phase 5: normalize + ReLU; write splits (or GE split on L==2)
        LN_WRITE(acc00, acc01, 0)
        LN_WRITE(acc10, acc11, 1)
        LN_WRITE(acc20, acc21, 2)
    }
}

// ---------------- dd aggregation partials (deterministic) ------------------
__global__ void k_dd_agg(const int* __restrict__ dd_src,
                         const int* __restrict__ inv,
                         const ushort_t* __restrict__ GEh,
                         const ushort_t* __restrict__ GEl,
                         float* __restrict__ parts)
{
    const int c  = threadIdx.x;
    const int e0 = blockIdx.x * (2048 / DD_BLOCKS);
    float s = 0.f;
    for (int e = e0; e < e0 + (2048 / DD_BLOCKS); ++e) {
        int b = inv[dd_src[e]];
        if (b >= 0) s += b2f(GEh[b * RANK + c]) + b2f(GEl[b * RANK + c]);
    }
    parts[blockIdx.x * RANK + c] = s;
}

// ---------------- device-node vector path -> c2 ----------------------------
__global__ void k_device(const float* __restrict__ parts,
                         const float* __restrict__ aug,
                         const float* __restrict__ infoW,
                         const float* __restrict__ infoB,
                         const float* __restrict__ ddW,
                         const float* __restrict__ ddB,
                         const float* __restrict__ normG,
                         const float* __restrict__ normB,
                         const float* __restrict__ predW1,
                         const float* __restrict__ predB1,
                         float* __restrict__ c2)
{
    __shared__ float sh[RANK];
    __shared__ float sdev[RANK];
    __shared__ float sred[RANK];
    const int n = threadIdx.x;

    float agg = 0.f;
    for (int p = 0; p < DD_BLOCKS; ++p) agg += parts[p * RANK + n];
    float info = infoB[n];
    for (int j = 0; j < 5; ++j) info += aug[j] * infoW[j * RANK + n];
    sh[n] = (agg + info) * (1.0f / 2049.0f);   // (agg + self) / (deg + 1)
    __syncthreads();

    float y = ddB[n];
    for (int k = 0; k < RANK; ++k) y += sh[k] * ddW[k * RANK + n];

    sred[n] = y; __syncthreads();
    for (int off = 128; off > 0; off >>= 1) {
        if (n < off) sred[n] += sred[n + off];
        __syncthreads();
    }
    float s = sred[0]; __syncthreads();
    sred[n] = y * y; __syncthreads();
    for (int off = 128; off > 0; off >>= 1) {
        if (n < off) sred[n] += sred[n + off];
        __syncthreads();
    }
    float q = sred[0]; __syncthreads();

    float m = s * (1.0f / 256.0f);
    float var = q * (1.0f / 256.0f) - m * m;
    if (var < 0.f) var = 0.f;
    float rs = rsqrtf(var + 1e-5f);
    float dev = (y - m) * rs * normG[n] + normB[n];
    if (dev < 0.f) dev = 0.f;
    sdev[n] = dev;
    __syncthreads();

    float o = predB1[n];
    for (int k = 0; k < RANK; ++k) o += sdev[k] * predW1[(RANK + k) * RANK + n];
    c2[n] = o;
}

// ---------------- final: out = relu(GE @ W1a + c2) . W2 + b2 ---------------
// block = 64 threads (1 wave) = 16 rows; split MFMA over full N=256
__global__ void k_pred(const ushort_t* __restrict__ GEh,
                       const ushort_t* __restrict__ GEl,
                       const ushort_t* __restrict__ W1h,   // [n][k] hi
                       const ushort_t* __restrict__ W1l,   // [n][k] lo
                       const float* __restrict__ c2,
                       const float* __restrict__ predW2,
                       const float* __restrict__ predB2,
                       float* __restrict__ out)
{
    const int lane = threadIdx.x;
    const int q4 = lane >> 4, l15 = lane & 15;
    const int m0 = blockIdx.x * 16;

    f32x4 acc[16];
    const f32x4 vzero = {0.f, 0.f, 0.f, 0.f};
    #pragma unroll
    for (int Nt = 0; Nt < 16; ++Nt) acc[Nt] = vzero;

    const ushort_t* ah = GEh + (m0 + l15) * RANK + q4 * 8;
    const ushort_t* al = GEl + (m0 + l15) * RANK + q4 * 8;
    const ushort_t* bh = W1h + l15 * RANK + q4 * 8;
    const ushort_t* bl = W1l + l15 * RANK + q4 * 8;
    #pragma unroll
    for (int ks = 0; ks < 8; ++ks) {
        mfma_ab Ah = *(const mfma_ab*)(ah + ks * 32);
        mfma_ab Al = *(const mfma_ab*)(al + ks * 32);
        #pragma unroll
        for (int Nt = 0; Nt < 16; ++Nt) {
            mfma_ab Bh = *(const mfma_ab*)(bh + Nt * 16 * RANK + ks * 32);
            mfma_ab Bl = *(const mfma_ab*)(bl + Nt * 16 * RANK + ks * 32);
            acc[Nt] = mfma_bf16(Ah, Bh, acc[Nt]);
            acc[Nt] = mfma_bf16(Al, Bh, acc[Nt]);
            acc[Nt] = mfma_bf16(Ah, Bl, acc[Nt]);
        }
    }

    float op0 = 0.f, op1 = 0.f, op2 = 0.f, op3 = 0.f;
    #pragma unroll
    for (int Nt = 0; Nt < 16; ++Nt) {
        int col = Nt * 16 + l15;
        float c2v = c2[col];
        float w2v = predW2[col];
        float h0 = fmaxf(acc[Nt][0] + c2v, 0.f);
        float h1 = fmaxf(acc[Nt][1] + c2v, 0.f);
        float h2 = fmaxf(acc[Nt][2] + c2v, 0.f);
        float h3 = fmaxf(acc[Nt][3] + c2v, 0.f);
        op0 += h0 * w2v; op1 += h1 * w2v; op2 += h2 * w2v; op3 += h3 * w2v;
    }
    #pragma unroll
    for (int mask = 1; mask <= 8; mask <<= 1) {
        op0 += __shfl_xor(op0, mask, 64);
        op1 += __shfl_xor(op1, mask, 64);
        op2 += __shfl_xor(op2, mask, 64);
        op3 += __shfl_xor(op3, mask, 64);
    }
    if (l15 == 0) {
        float b2 = predB2[0];
        out[m0 + q4 * 4 + 0] = op0 + b2;
        out[m0 + q4 * 4 + 1] = op1 + b2;
        out[m0 + q4 * 4 + 2] = op2 + b2;
        out[m0 + q4 * 4 + 3] = op3 + b2;
    }
}

extern "C" void kernel_launch(void* const* d_in, const int* in_sizes, int n_in,
                              void* d_out, int out_size, void* d_ws, size_t ws_size,
                              hipStream_t stream) {
    const int* features  = (const int*)d_in[0];
    const int* key_ids   = (const int*)d_in[1];
    const int* dd_src    = (const int*)d_in[4];
    const float* emb     = (const float*)d_in[5];
    const float* sageW   = (const float*)d_in[6];
    const float* sageB   = (const float*)d_in[7];
    const float* lnG     = (const float*)d_in[8];
    const float* lnB     = (const float*)d_in[9];
    const float* ddW     = (const float*)d_in[10];
    const float* ddB     = (const float*)d_in[11];
    const float* normG   = (const float*)d_in[12];
    const float* normB   = (const float*)d_in[13];
    const float* infoW   = (const float*)d_in[14];
    const float* infoB   = (const float*)d_in[15];
    const float* aug     = (const float*)d_in[16];
    const float* predW1  = (const float*)d_in[17];
    const float* predB1  = (const float*)d_in[18];
    const float* predW2  = (const float*)d_in[19];
    const float* predB2  = (const float*)d_in[20];

    char* ws = (char*)d_ws;
    ushort_t* GEh   = (ushort_t*)(ws + GEH_OFF);
    ushort_t* GEl   = (ushort_t*)(ws + GEL_OFF);
    ushort_t* WTh   = (ushort_t*)(ws + WTH_OFF);
    ushort_t* WTl   = (ushort_t*)(ws + WTL_OFF);
    int*      inv   = (int*)(ws + INV_OFF);
    float*    parts = (float*)(ws + PARTS_OFF);
    float*    c2    = (float*)(ws + C2_OFF);
    float*    outp  = (float*)d_out;

    k_init_inv<<<62, 256, 0, stream>>>(inv);
    k_scatter<<<32, 256, 0, stream>>>(key_ids, inv);
    k_prep_w<<<64, 256, 0, stream>>>(sageW, predW1, WTh, WTl);
    k_graph_reader<<<(NB + GR_G - 1) / GR_G, 512, 0, stream>>>(
        features, emb, WTh, WTl, sageB, lnG, lnB, GEh, GEl);
    k_dd_agg<<<DD_BLOCKS, 256, 0, stream>>>(dd_src, inv, GEh, GEl, parts);
    k_device<<<1, 256, 0, stream>>>(parts, aug, infoW, infoB, ddW, ddB,
                                    normG, normB, predW1, predB1, c2);
    k_pred<<<NB / 16, 64, 0, stream>>>(GEh, GEl, WTh + 3 * 65536, WTl + 3 * 65536,
                                       c2, predW2, predB2, outp);
}